// Round 10
// baseline (231.464 us; speedup 1.0000x reference)
//
#include <hip/hip_runtime.h>

// ACE symmetrizer, fused: b[r,f,n] = sum_m cg[r,m] * A[f,m,n] for 5 (A, CG0, CG1)
// groups in ONE kernel. Memory-bound: ~500MB read + 537MB write -> ~165us floor.
//
// Round-10 = round-7 (207us, best) with ONE change: PLAIN stores instead of
// nontemporal. Theory: nt stores bypass L2 write-allocation -> 32 scattered
// 512B bursts per wave go straight to DRAM (row-buffer thrash across ~32K
// concurrent streams). Plain stores aggregate in L2 (32MB) and drain in
// larger bank-friendly batches — the harness fill kernels (6.65 TB/s) and
// the m13 copy (6.3 TB/s) both use plain stores. A-reuse argument for nt is
// void: round-6 showed load caching is neutral (A has no intra-dispatch reuse).
//
// Everything else identical to round 7: f32x2/lane, acc[32] (~95 VGPR,
// 4 waves/SIMD), 4-deep clamped prefetch, compile-time M, 8192 blocks
// (op, f, n-half), heavy-ops-first, nt loads.

typedef float f32x2 __attribute__((ext_vector_type(2)));

#define NN 1024

// output float offsets (return order: b0 x5 then b1 x5)
#define O0_0 0UL
#define O0_1 8388608UL
#define O0_2 16777216UL
#define O0_3 25165824UL
#define O0_4 29360128UL
#define O1_0 33554432UL
#define O1_1 58720256UL
#define O1_2 83886080UL
#define O1_3 109051904UL
#define O1_4 121634816UL

// padded cgT float offsets in ws: 32*MP per op, MP = {12,28,52,28,48}
#define WP_0 0
#define WP_1 384
#define WP_2 1280
#define WP_3 2944
#define WP_4 3840
#define WP_TOT 5376

__global__ __launch_bounds__(256)
void cg_transpose(const float* __restrict__ c00, const float* __restrict__ c01,
                  const float* __restrict__ c02, const float* __restrict__ c03,
                  const float* __restrict__ c04,
                  const float* __restrict__ c10, const float* __restrict__ c11,
                  const float* __restrict__ c12, const float* __restrict__ c13,
                  const float* __restrict__ c14,
                  float* __restrict__ w)
{
    int t = blockIdx.x * 256 + threadIdx.x;
    if (t >= WP_TOT) return;
    int M, off; const float* g0; const float* g1;
    if      (t < WP_1) { M = 9;  off = WP_0; g0 = c00; g1 = c10; }
    else if (t < WP_2) { M = 25; off = WP_1; g0 = c01; g1 = c11; }
    else if (t < WP_3) { M = 49; off = WP_2; g0 = c02; g1 = c12; }
    else if (t < WP_4) { M = 27; off = WP_3; g0 = c03; g1 = c13; }
    else               { M = 45; off = WP_4; g0 = c04; g1 = c14; }
    int loc = t - off;
    int m = loc >> 5, r = loc & 31;
    float v = 0.f;
    if (m < M) v = (r < 8) ? g0[r * M + m] : g1[(r - 8) * M + m];
    w[t] = v;
}

template<int M, int MP>
__device__ __forceinline__ void run_op(const float* __restrict__ Af,  // A + f*M*NN + n0
                                       const float* __restrict__ cg,  // cgT + WP_op, [MP][32]
                                       float* __restrict__ p0,        // out + o0 + f*NN + n0
                                       float* __restrict__ p1,        // out + o1 + f*NN + n0
                                       size_t stride)                 // F*NN
{
    const f32x2* ap = reinterpret_cast<const f32x2*>(Af);

    f32x2 buf[4];
#pragma unroll
    for (int i = 0; i < 4; ++i) {
        const int mi = (i < M) ? i : (M - 1);
        buf[i] = __builtin_nontemporal_load(ap + (size_t)mi * (NN / 2));
    }

    f32x2 acc[32];
#pragma unroll
    for (int r = 0; r < 32; ++r) acc[r] = (f32x2)(0.f);

#pragma unroll 1
    for (int m = 0; m < MP; m += 4) {
#pragma unroll
        for (int i = 0; i < 4; ++i) {
            const f32x2 cur = buf[i];
            int nm = m + 4 + i;
            nm = (nm < M) ? nm : (M - 1);            // clamped prefetch
            buf[i] = __builtin_nontemporal_load(ap + (size_t)nm * (NN / 2));
            const float* c = cg + (size_t)(m + i) * 32;   // uniform -> s_load x2
#pragma unroll
            for (int r = 0; r < 32; ++r) {
                const float cr = c[r];
                acc[r].x = fmaf(cr, cur.x, acc[r].x);
                acc[r].y = fmaf(cr, cur.y, acc[r].y);
            }
        }
    }

    // PLAIN stores (the one change vs round 7): allocate in L2, let the cache
    // aggregate and drain to HBM in bank-friendly batches.
#pragma unroll
    for (int r = 0; r < 8; ++r)
        *reinterpret_cast<f32x2*>(p0 + r * stride) = acc[r];
#pragma unroll
    for (int r = 0; r < 24; ++r)
        *reinterpret_cast<f32x2*>(p1 + r * stride) = acc[8 + r];
}

__global__ __launch_bounds__(256)
void ace_sym_all(const float* __restrict__ A0, const float* __restrict__ A1,
                 const float* __restrict__ A2, const float* __restrict__ A3,
                 const float* __restrict__ A4,
                 const float* __restrict__ cgT, float* __restrict__ out)
{
    const int bid = blockIdx.x;
    // block covers 512 n: half = bid&1 selects n in [0,512) or [512,1024)
    const int n0base = (int)threadIdx.x * 2;

    // heavy-first: M=49 (F=1024), M=45 (512), M=25 (1024), M=27 (512), M=9 (1024)
    if (bid < 2048) {
        const size_t f = bid >> 1;
        const int n0 = ((bid & 1) << 9) + n0base;
        run_op<49, 52>(A2 + f * 49 * NN + n0, cgT + WP_2,
                       out + O0_2 + f * NN + n0, out + O1_2 + f * NN + n0,
                       (size_t)1024 * NN);
    } else if (bid < 3072) {
        const int loc = bid - 2048;
        const size_t f = loc >> 1;
        const int n0 = ((loc & 1) << 9) + n0base;
        run_op<45, 48>(A4 + f * 45 * NN + n0, cgT + WP_4,
                       out + O0_4 + f * NN + n0, out + O1_4 + f * NN + n0,
                       (size_t)512 * NN);
    } else if (bid < 5120) {
        const int loc = bid - 3072;
        const size_t f = loc >> 1;
        const int n0 = ((loc & 1) << 9) + n0base;
        run_op<25, 28>(A1 + f * 25 * NN + n0, cgT + WP_1,
                       out + O0_1 + f * NN + n0, out + O1_1 + f * NN + n0,
                       (size_t)1024 * NN);
    } else if (bid < 6144) {
        const int loc = bid - 5120;
        const size_t f = loc >> 1;
        const int n0 = ((loc & 1) << 9) + n0base;
        run_op<27, 28>(A3 + f * 27 * NN + n0, cgT + WP_3,
                       out + O0_3 + f * NN + n0, out + O1_3 + f * NN + n0,
                       (size_t)512 * NN);
    } else {
        const int loc = bid - 6144;
        const size_t f = loc >> 1;
        const int n0 = ((loc & 1) << 9) + n0base;
        run_op<9, 12>(A0 + f * 9 * NN + n0, cgT + WP_0,
                      out + O0_0 + f * NN + n0, out + O1_0 + f * NN + n0,
                      (size_t)1024 * NN);
    }
}

extern "C" void kernel_launch(void* const* d_in, const int* in_sizes, int n_in,
                              void* d_out, int out_size, void* d_ws, size_t ws_size,
                              hipStream_t stream)
{
    const float* A0 = (const float*)d_in[0];
    const float* A1 = (const float*)d_in[1];
    const float* A2 = (const float*)d_in[2];
    const float* A3 = (const float*)d_in[3];
    const float* A4 = (const float*)d_in[4];

    float* wsT = (float*)d_ws;

    hipLaunchKernelGGL(cg_transpose, dim3((WP_TOT + 255) / 256), dim3(256), 0, stream,
                       (const float*)d_in[5], (const float*)d_in[6], (const float*)d_in[7],
                       (const float*)d_in[8], (const float*)d_in[9],
                       (const float*)d_in[10], (const float*)d_in[11], (const float*)d_in[12],
                       (const float*)d_in[13], (const float*)d_in[14], wsT);

    hipLaunchKernelGGL(ace_sym_all, dim3(8192), dim3(256), 0, stream,
                       A0, A1, A2, A3, A4, (const float*)wsT, (float*)d_out);
}

// Round 11
// 219.713 us; speedup vs baseline: 1.0535x; 1.0535x over previous
//
#include <hip/hip_runtime.h>

// ACE symmetrizer, fused: b[r,f,n] = sum_m cg[r,m] * A[f,m,n] for 5 (A, CG0, CG1)
// groups in ONE kernel. Memory-bound: ~500MB read + 537MB write -> ~165us floor.
//
// Round-11 = round-7 (207us, best) with ONE structural change: 512-thread
// blocks covering the FULL 1024-n row (was 256 threads x half-row).
// Every A m-row read and every output r-row write is now a full 4KB
// page-aligned unit owned by one block (the 6.3TB/s copy pattern), instead
// of 2KB half-pages interleaved with an uncorrelated sibling block.
// Register profile unchanged: acc[32] x f32x2 = 64 + buf 8 + addr ~95 VGPR
// -> 4 waves/SIMD. nt loads + nt stores (round-10 A/B: nt stores win by 24us).

typedef float f32x2 __attribute__((ext_vector_type(2)));

#define NN 1024

// output float offsets (return order: b0 x5 then b1 x5)
#define O0_0 0UL
#define O0_1 8388608UL
#define O0_2 16777216UL
#define O0_3 25165824UL
#define O0_4 29360128UL
#define O1_0 33554432UL
#define O1_1 58720256UL
#define O1_2 83886080UL
#define O1_3 109051904UL
#define O1_4 121634816UL

// padded cgT float offsets in ws: 32*MP per op, MP = {12,28,52,28,48}
#define WP_0 0
#define WP_1 384
#define WP_2 1280
#define WP_3 2944
#define WP_4 3840
#define WP_TOT 5376

__global__ __launch_bounds__(256)
void cg_transpose(const float* __restrict__ c00, const float* __restrict__ c01,
                  const float* __restrict__ c02, const float* __restrict__ c03,
                  const float* __restrict__ c04,
                  const float* __restrict__ c10, const float* __restrict__ c11,
                  const float* __restrict__ c12, const float* __restrict__ c13,
                  const float* __restrict__ c14,
                  float* __restrict__ w)
{
    int t = blockIdx.x * 256 + threadIdx.x;
    if (t >= WP_TOT) return;
    int M, off; const float* g0; const float* g1;
    if      (t < WP_1) { M = 9;  off = WP_0; g0 = c00; g1 = c10; }
    else if (t < WP_2) { M = 25; off = WP_1; g0 = c01; g1 = c11; }
    else if (t < WP_3) { M = 49; off = WP_2; g0 = c02; g1 = c12; }
    else if (t < WP_4) { M = 27; off = WP_3; g0 = c03; g1 = c13; }
    else               { M = 45; off = WP_4; g0 = c04; g1 = c14; }
    int loc = t - off;
    int m = loc >> 5, r = loc & 31;
    float v = 0.f;
    if (m < M) v = (r < 8) ? g0[r * M + m] : g1[(r - 8) * M + m];
    w[t] = v;
}

template<int M, int MP>
__device__ __forceinline__ void run_op(const float* __restrict__ Af,  // A + f*M*NN + n0
                                       const float* __restrict__ cg,  // cgT + WP_op, [MP][32]
                                       float* __restrict__ p0,        // out + o0 + f*NN + n0
                                       float* __restrict__ p1,        // out + o1 + f*NN + n0
                                       size_t stride)                 // F*NN
{
    const f32x2* ap = reinterpret_cast<const f32x2*>(Af);

    f32x2 buf[4];
#pragma unroll
    for (int i = 0; i < 4; ++i) {
        const int mi = (i < M) ? i : (M - 1);
        buf[i] = __builtin_nontemporal_load(ap + (size_t)mi * (NN / 2));
    }

    f32x2 acc[32];
#pragma unroll
    for (int r = 0; r < 32; ++r) acc[r] = (f32x2)(0.f);

#pragma unroll 1
    for (int m = 0; m < MP; m += 4) {
#pragma unroll
        for (int i = 0; i < 4; ++i) {
            const f32x2 cur = buf[i];
            int nm = m + 4 + i;
            nm = (nm < M) ? nm : (M - 1);            // clamped prefetch (L2 hit)
            buf[i] = __builtin_nontemporal_load(ap + (size_t)nm * (NN / 2));
            const float* c = cg + (size_t)(m + i) * 32;   // uniform -> s_load x2
#pragma unroll
            for (int r = 0; r < 32; ++r) {
                const float cr = c[r];
                acc[r].x = fmaf(cr, cur.x, acc[r].x);
                acc[r].y = fmaf(cr, cur.y, acc[r].y);
            }
        }
    }

#pragma unroll
    for (int r = 0; r < 8; ++r)
        __builtin_nontemporal_store(acc[r], reinterpret_cast<f32x2*>(p0 + r * stride));
#pragma unroll
    for (int r = 0; r < 24; ++r)
        __builtin_nontemporal_store(acc[8 + r], reinterpret_cast<f32x2*>(p1 + r * stride));
}

__global__ __launch_bounds__(512)
void ace_sym_all(const float* __restrict__ A0, const float* __restrict__ A1,
                 const float* __restrict__ A2, const float* __restrict__ A3,
                 const float* __restrict__ A4,
                 const float* __restrict__ cgT, float* __restrict__ out)
{
    const int bid = blockIdx.x;
    const int n0 = (int)threadIdx.x * 2;   // 512 threads x f32x2 = full 1024-n row

    // heavy-first: M=49 (F=1024), M=45 (512), M=25 (1024), M=27 (512), M=9 (1024)
    if (bid < 1024) {
        const size_t f = bid;
        run_op<49, 52>(A2 + f * 49 * NN + n0, cgT + WP_2,
                       out + O0_2 + f * NN + n0, out + O1_2 + f * NN + n0,
                       (size_t)1024 * NN);
    } else if (bid < 1536) {
        const size_t f = bid - 1024;
        run_op<45, 48>(A4 + f * 45 * NN + n0, cgT + WP_4,
                       out + O0_4 + f * NN + n0, out + O1_4 + f * NN + n0,
                       (size_t)512 * NN);
    } else if (bid < 2560) {
        const size_t f = bid - 1536;
        run_op<25, 28>(A1 + f * 25 * NN + n0, cgT + WP_1,
                       out + O0_1 + f * NN + n0, out + O1_1 + f * NN + n0,
                       (size_t)1024 * NN);
    } else if (bid < 3072) {
        const size_t f = bid - 2560;
        run_op<27, 28>(A3 + f * 27 * NN + n0, cgT + WP_3,
                       out + O0_3 + f * NN + n0, out + O1_3 + f * NN + n0,
                       (size_t)512 * NN);
    } else {
        const size_t f = bid - 3072;
        run_op<9, 12>(A0 + f * 9 * NN + n0, cgT + WP_0,
                      out + O0_0 + f * NN + n0, out + O1_0 + f * NN + n0,
                      (size_t)1024 * NN);
    }
}

extern "C" void kernel_launch(void* const* d_in, const int* in_sizes, int n_in,
                              void* d_out, int out_size, void* d_ws, size_t ws_size,
                              hipStream_t stream)
{
    const float* A0 = (const float*)d_in[0];
    const float* A1 = (const float*)d_in[1];
    const float* A2 = (const float*)d_in[2];
    const float* A3 = (const float*)d_in[3];
    const float* A4 = (const float*)d_in[4];

    float* wsT = (float*)d_ws;

    hipLaunchKernelGGL(cg_transpose, dim3((WP_TOT + 255) / 256), dim3(256), 0, stream,
                       (const float*)d_in[5], (const float*)d_in[6], (const float*)d_in[7],
                       (const float*)d_in[8], (const float*)d_in[9],
                       (const float*)d_in[10], (const float*)d_in[11], (const float*)d_in[12],
                       (const float*)d_in[13], (const float*)d_in[14], wsT);

    hipLaunchKernelGGL(ace_sym_all, dim3(4096), dim3(512), 0, stream,
                       A0, A1, A2, A3, A4, (const float*)wsT, (float*)d_out);
}